// Round 1
// 62.427 us; speedup vs baseline: 1.1853x; 1.1853x over previous
//
#include <hip/hip_runtime.h>

// LiftingScheme == plain 3x3 same-padding conv2d (predict/update coeffs cancel
// exactly to w): out[n,o,i,j] = sum_{c,kh,kw} w[o,c,kh,kw]*x[n,c,i+kh-1,j+kw-1]
//
// Round-3: round-2 was latency-bound, NOT pipe-bound: 224 blocks x 4 waves =
// 0.875 waves/SIMD, so every SMEM(weight)/LDS(x) lgkmcnt stall and the staging
// loop's HBM latency is fully exposed (~33us vs a ~1.7us VALU wall).
// Changes:
//  1. 1024-thread blocks, 16 waves = 4 o-quads x 4 C-chunks (8 ch each).
//     Forced co-residency -> 4 waves/SIMD; stalls of one wave hide under
//     another's FMAs. Per-wave LDS:VALU ratio unchanged (still 4 o/wave,
//     6 ds_read_b64 : 72 FMA per channel -> VALU-bound per CU).
//  2. C-partials reduced through LDS (reusing the x tile buffer) with a
//     stride-10-float layout (8B aligned, bank-spread) -> no atomics, no
//     extra kernel launch, out written exactly once.
// Grid stays 224 blocks (4 og, 28 row-pairs, 2 n); staging now 1024-wide.

namespace {
constexpr int Cc = 32, Hh = 56, Ww = 56, Oo = 64;

constexpr int RSTRIDE = 10;   // floats per lane slot in reduction scratch (40B: 8B-aligned, bank-spread)
constexpr int REGION  = 576;  // >= 56*RSTRIDE, per (cchunk,oq) partial region

__global__ __launch_bounds__(1024, 4)
void lifting_conv_kernel(const float* __restrict__ x,
                         const float* __restrict__ w,
                         float* __restrict__ out)
{
    // x tile: [C][4 padded rows][60 (58 used)] = 7680 floats = 30 KB.
    // Reused after the c-loop as reduction scratch: 12 regions * 576 = 6912 floats.
    __shared__ float xs[Cc * 4 * 60];

    const int tid = threadIdx.x;
    const int og  = blockIdx.x;   // 0..3  -> o0 = 16*og
    const int ip  = blockIdx.y;   // 0..27 -> rows 2*ip, 2*ip+1
    const int n   = blockIdx.z;   // 0..1
    const int i0  = ip * 2;

    // ---- stage x rows i0-1..i0+2 (zero-padded), cols -1..56 (zero-padded) ----
    for (int e = tid; e < Cc * 4 * 58; e += 1024) {
        const int c   = e / (4 * 58);
        const int rem = e - c * (4 * 58);
        const int r   = rem / 58;
        const int jj  = rem - r * 58;
        const int h   = i0 - 1 + r;
        const int col = jj - 1;
        float v = 0.0f;
        if ((unsigned)h < (unsigned)Hh && (unsigned)col < (unsigned)Ww)
            v = x[((n * Cc + c) * Hh + h) * Ww + col];
        xs[(c * 4 + r) * 60 + jj] = v;
    }
    __syncthreads();

    const int lane = tid & 63;
    const int wv   = tid >> 6;            // wave id 0..15
    const int oq   = wv & 3;              // o-quad within the block's 16 o
    const int cch  = wv >> 2;             // c-chunk 0..3 (8 channels each)
    const bool act = lane < 56;           // 56 active lanes per wave
    const int lact = act ? lane : 0;      // inactive lanes compute harmlessly
    const int rsub = (lact >= 28) ? 1 : 0;
    const int cp   = lact - rsub * 28;    // column pair 0..27
    const int col0 = cp * 2;

    // wave-uniform bases -> scalar (SMEM) weight loads, zero LDS spent on weights
    const int o_base = __builtin_amdgcn_readfirstlane(og * 16 + oq * 4);
    const int cbeg   = __builtin_amdgcn_readfirstlane(cch * 8);
    const float* __restrict__ wb = w + ((size_t)o_base * Cc + cbeg) * 9;

    float acc[4][2];
    #pragma unroll
    for (int i = 0; i < 4; ++i) { acc[i][0] = 0.f; acc[i][1] = 0.f; }

    const float* xbase = &xs[cbeg * 240 + rsub * 60 + col0];

    #pragma unroll 2
    for (int cc = 0; cc < 8; ++cc) {
        const float* xr = xbase + cc * 240;
        // 3 rows x 4 cols register window (6x ds_read_b64, 8B-aligned)
        const float2 r0a = *(const float2*)(xr);
        const float2 r0b = *(const float2*)(xr + 2);
        const float2 r1a = *(const float2*)(xr + 60);
        const float2 r1b = *(const float2*)(xr + 62);
        const float2 r2a = *(const float2*)(xr + 120);
        const float2 r2b = *(const float2*)(xr + 122);

        #pragma unroll
        for (int oo = 0; oo < 4; ++oo) {
            const float* wc = wb + (oo * Cc + cc) * 9;  // wave-uniform address
            const float w0 = wc[0], w1 = wc[1], w2 = wc[2],
                        w3 = wc[3], w4 = wc[4], w5 = wc[5],
                        w6 = wc[6], w7 = wc[7], w8 = wc[8];
            acc[oo][0] += w0 * r0a.x + w1 * r0a.y + w2 * r0b.x
                        + w3 * r1a.x + w4 * r1a.y + w5 * r1b.x
                        + w6 * r2a.x + w7 * r2a.y + w8 * r2b.x;
            acc[oo][1] += w0 * r0a.y + w1 * r0b.x + w2 * r0b.y
                        + w3 * r1a.y + w4 * r1b.x + w5 * r1b.y
                        + w6 * r2a.y + w7 * r2b.x + w8 * r2b.y;
        }
    }

    // ---- reduce the 4 C-chunk partials through LDS (xs is dead now) ----
    __syncthreads();   // all x reads done before xs is overwritten

    if (cch > 0 && act) {
        float* p = &xs[((cch - 1) * 4 + oq) * REGION + lane * RSTRIDE];
        #pragma unroll
        for (int oo = 0; oo < 4; ++oo)
            *(float2*)(p + oo * 2) = make_float2(acc[oo][0], acc[oo][1]);
    }
    __syncthreads();

    if (cch == 0 && act) {
        #pragma unroll
        for (int pi = 0; pi < 3; ++pi) {
            const float* p = &xs[(pi * 4 + oq) * REGION + lane * RSTRIDE];
            #pragma unroll
            for (int oo = 0; oo < 4; ++oo) {
                const float2 v = *(const float2*)(p + oo * 2);
                acc[oo][0] += v.x;
                acc[oo][1] += v.y;
            }
        }
        const int row = i0 + rsub;
        #pragma unroll
        for (int oo = 0; oo < 4; ++oo) {
            float2 v; v.x = acc[oo][0]; v.y = acc[oo][1];
            *(float2*)(out + ((size_t)(n * Oo + o_base + oo) * Hh + row) * Ww + col0) = v;
        }
    }
}
} // namespace

extern "C" void kernel_launch(void* const* d_in, const int* in_sizes, int n_in,
                              void* d_out, int out_size, void* d_ws, size_t ws_size,
                              hipStream_t stream)
{
    const float* x = (const float*)d_in[0];   // (2,32,56,56) fp32
    const float* w = (const float*)d_in[1];   // (64,32,3,3) fp32
    float* out = (float*)d_out;               // (2,64,56,56) fp32

    dim3 grid(4, 28, 2);  // (o-groups of 16, row-pairs, n) = 224 blocks
    lifting_conv_kernel<<<grid, 1024, 0, stream>>>(x, w, out);
}